// Round 19
// baseline (242.525 us; speedup 1.0000x reference)
//
#include <hip/hip_runtime.h>
#include <stdint.h>

// Problem sizes.
static constexpr int Bn = 4096;
static constexpr int Dn = 5000;
static constexpr int Hn = 2000;
static constexpr int Ln = 50;
static constexpr int XW = 80;      // u64 words covering D (5120 bits)
static constexpr int Hpad = 2048;  // padded H
static constexpr int Dpad = 5120;  // padded D

typedef int v4i __attribute__((ext_vector_type(4)));
typedef int v16i __attribute__((ext_vector_type(16)));

#if defined(__has_builtin)
#if __has_builtin(__builtin_amdgcn_global_load_lds)
#define HAVE_GLOAD_LDS 1
#endif
#endif

#ifdef HAVE_GLOAD_LDS
__device__ __forceinline__ void gload16(const uint8_t* g, uint8_t* l) {
  // async global->LDS, 16B/lane; LDS dest = wave-uniform base + lane*16.
  __builtin_amdgcn_global_load_lds(
      (const __attribute__((address_space(1))) uint32_t*)g,
      (__attribute__((address_space(3))) uint32_t*)l, 16, 0, 0);
}
#endif

__device__ __forceinline__ int popc_acc(uint64_t v, int acc) {
  acc = __builtin_popcount((uint32_t)v) + acc;
  acc = __builtin_popcount((uint32_t)(v >> 32)) + acc;
  return acc;
}

// ---------- K-major i8 packing (R17-verified) ----------
__global__ void k_pack_xT(const float* __restrict__ x, uint8_t* __restrict__ xiT) {
  int g = (int)blockIdx.x * 256 + (int)threadIdx.x;
  int kb = g >> 12;          // Bn = 4096
  int row = g & 4095;
  if (kb >= Dpad / 16) return;
  uint8_t o[16];
  int c0 = kb * 16;
  if (c0 + 15 < Dn) {
#pragma unroll
    for (int q = 0; q < 4; ++q) {
      float4 v = *(const float4*)(x + (size_t)row * Dn + c0 + q * 4);
      o[q * 4 + 0] = v.x >= 0.5f;
      o[q * 4 + 1] = v.y >= 0.5f;
      o[q * 4 + 2] = v.z >= 0.5f;
      o[q * 4 + 3] = v.w >= 0.5f;
    }
  } else {
#pragma unroll
    for (int e = 0; e < 16; ++e) {
      int c = c0 + e;
      o[e] = (c < Dn) ? (x[(size_t)row * Dn + c] >= 0.5f ? 1 : 0) : 0;
    }
  }
  *(uint4*)(xiT + ((size_t)kb * Bn + row) * 16) = *(uint4*)o;
}

__global__ __launch_bounds__(256) void k_pack_w_dualT(const float* __restrict__ W,
                                                      uint8_t* __restrict__ wi8T,
                                                      uint8_t* __restrict__ wtdT) {
  int d = (int)blockIdx.x * 256 + (int)threadIdx.x;  // 0..5119
  int j0 = (int)blockIdx.y * 64;                     // 32 blocks of 64 j
  bool dv = d < Dn;
  int dc = d >> 4, de = d & 15;
  uint64_t colbits = 0;
  for (int r = 0; r < 64; ++r) {
    int j = j0 + r;
    float v = (j < Hn && dv) ? W[(size_t)j * Dn + d] : 0.0f;
    uint8_t bit = (v >= 0.5f) ? 1 : 0;
    wi8T[((size_t)dc * Hpad + j) * 16 + de] = bit;
    colbits |= ((uint64_t)bit) << r;
  }
#pragma unroll
  for (int q = 0; q < 4; ++q) {
    uint32_t u[4];
#pragma unroll
    for (int s = 0; s < 4; ++s) {
      uint32_t nib = (uint32_t)((colbits >> (q * 16 + s * 4)) & 0xFull);
      u[s] = (nib & 1u) | (((nib >> 1) & 1u) << 8) | (((nib >> 2) & 1u) << 16) |
             (((nib >> 3) & 1u) << 24);
    }
    *(uint4*)(wtdT + (((size_t)(j0 >> 4) + q) * Dpad + d) * 16) =
        make_uint4(u[0], u[1], u[2], u[3]);
  }
}

// ---------- bit packing (fallback tier) ----------
__global__ void k_pack_x(const float* __restrict__ x, uint64_t* __restrict__ xb2) {
  int g = (int)((blockIdx.x * blockDim.x + threadIdx.x) >> 6);
  int lane = (int)(threadIdx.x & 63);
  constexpr int nq = XW >> 2;
  int row = g / nq;
  int q = g - row * nq;
  if (row >= Bn) return;
  int w0 = q << 2;
  unsigned long long m[4];
#pragma unroll
  for (int e = 0; e < 4; ++e) {
    int col = ((w0 + e) << 6) + lane;
    float v = (col < Dn) ? x[(size_t)row * Dn + col] : 0.0f;
    m[e] = __ballot(v >= 0.5f);
  }
  if (lane < 4) {
    unsigned long long mv = m[0];
    mv = (lane == 1) ? m[1] : mv;
    mv = (lane == 2) ? m[2] : mv;
    mv = (lane == 3) ? m[3] : mv;
    int w = w0 + lane;
    xb2[((size_t)(w >> 1) * Bn + row) * 2 + (w & 1)] = mv;
  }
}

__global__ void k_pack_w(const float* __restrict__ W, uint64_t* __restrict__ wbT) {
  int g = (int)((blockIdx.x * blockDim.x + threadIdx.x) >> 6);
  int lane = (int)(threadIdx.x & 63);
  constexpr int nq = XW >> 2;
  int row = g / nq;
  int q = g - row * nq;
  if (row >= Hn) return;
  int w0 = q << 2;
  unsigned long long m[4];
#pragma unroll
  for (int e = 0; e < 4; ++e) {
    int col = ((w0 + e) << 6) + lane;
    float v = (col < Dn) ? W[(size_t)row * Dn + col] : 0.0f;
    m[e] = __ballot(v >= 0.5f);
  }
  if (lane < 4) {
    unsigned long long mv = m[0];
    mv = (lane == 1) ? m[1] : mv;
    mv = (lane == 2) ? m[2] : mv;
    mv = (lane == 3) ? m[3] : mv;
    wbT[(size_t)(w0 + lane) * Hpad + row] = mv;
  }
}

__global__ void k_transp(const uint64_t* __restrict__ wbT, uint32_t* __restrict__ wt32) {
  int g = (int)((blockIdx.x * blockDim.x + threadIdx.x) >> 6);
  int lane = (int)(threadIdx.x & 63);
  int w = g % XW;
  int jc = g / XW;
  if (jc >= Hpad / 64) return;
  uint64_t word = wbT[(size_t)w * Hpad + jc * 64 + lane];
  uint64_t mym = 0;
#pragma unroll
  for (int e = 0; e < 64; ++e) {
    unsigned long long m = __ballot((word >> e) & 1ull);
    mym = (lane == e) ? m : mym;
  }
  int d = w * 64 + lane;
  wt32[(size_t)(jc * 2) * Dpad + d] = (uint32_t)mym;
  wt32[(size_t)(jc * 2 + 1) * Dpad + d] = (uint32_t)(mym >> 32);
}

__global__ void k_pack_fwT(const float* __restrict__ cw, float* __restrict__ fwT) {
  int idx = blockIdx.x * blockDim.x + threadIdx.x;
  if (idx >= Hn * 64) return;
  int j = idx >> 6, l = idx & 63;
  float v = 0.0f;
  if (l < Ln) {
    float t = 2.0f * cw[(size_t)l * Hn + j];
    v = 1.0f / (1.0f + expf(-t));
  }
  fwT[idx] = v;
}

__global__ void k_zero(float* __restrict__ p, int n) {
  int i = blockIdx.x * blockDim.x + threadIdx.x;
  if (i < n) p[i] = 0.0f;
}

// ====== BK=128 i8 MFMA GEMM, K-major LDS, COUNTED-vmcnt pipeline (T4) ======
// Block 128x128, 4 waves. LDS 2x16KB per matrix (64KB). Prologue stages 2
// tiles (16 loads in flight). Per tile: {setprio(1); 16 MFMA; setprio(0);
// s_barrier; STAGE(t+2) [8 gload16]; s_waitcnt vmcnt(8); s_barrier} — tile
// t+1's loads retire at the counted wait while t+2's stay in flight across
// BOTH barriers and under the next MFMA cluster. Never drains to 0 mid-loop.
// Conflict-free K-major fragment reads (R17): 32 lanes x contiguous 16B.

#ifdef HAVE_GLOAD_LDS
#define GEMM_PIPE(AROWS, BROWS, NT, Abase, Bbase)                               \
  const uint8_t* aS = (Abase) + ((size_t)bm * 128 + lane) * 16;                \
  const uint8_t* bS = (Bbase) + ((size_t)bn * 128 + lane) * 16;                \
  int kqw = 2 * wv;                                                            \
  int arow = wm * 64 + (lane & 31);                                            \
  int brow = wn * 64 + (lane & 31);                                            \
  int khalf = lane >> 5;                                                       \
  auto STAGE = [&](int buf, int tt) {                                          \
    _Pragma("unroll") for (int i = 0; i < 2; ++i) {                            \
      _Pragma("unroll") for (int c = 0; c < 2; ++c) {                          \
        gload16(aS + (((size_t)tt * 8 + kqw + i) * (AROWS) + c * 64) * 16,     \
                As + buf * 16384 + (kqw + i) * 2048 + c * 1024);               \
        gload16(bS + (((size_t)tt * 8 + kqw + i) * (BROWS) + c * 64) * 16,     \
                Bs + buf * 16384 + (kqw + i) * 2048 + c * 1024);               \
      }                                                                        \
    }                                                                          \
  };                                                                           \
  STAGE(0, 0);                                                                 \
  STAGE(1, 1);                                                                 \
  asm volatile("s_waitcnt vmcnt(8)" ::: "memory");                             \
  __builtin_amdgcn_sched_barrier(0);                                           \
  __builtin_amdgcn_s_barrier();                                                \
  __builtin_amdgcn_sched_barrier(0);                                           \
  _Pragma("unroll 1") for (int t = 0; t < (NT); ++t) {                         \
    int cur = t & 1;                                                           \
    const uint8_t* Ab = As + cur * 16384 + khalf * 2048;                       \
    const uint8_t* Bb = Bs + cur * 16384 + khalf * 2048;                       \
    __builtin_amdgcn_s_setprio(1);                                             \
    _Pragma("unroll") for (int kk = 0; kk < 4; ++kk) {                         \
      v4i a0 = *(const v4i*)(Ab + kk * 4096 + arow * 16);                      \
      v4i a1 = *(const v4i*)(Ab + kk * 4096 + (arow + 32) * 16);               \
      v4i b0 = *(const v4i*)(Bb + kk * 4096 + brow * 16);                      \
      v4i b1 = *(const v4i*)(Bb + kk * 4096 + (brow + 32) * 16);               \
      acc[0][0] = __builtin_amdgcn_mfma_i32_32x32x32_i8(a0, b0, acc[0][0], 0, 0, 0); \
      acc[0][1] = __builtin_amdgcn_mfma_i32_32x32x32_i8(a0, b1, acc[0][1], 0, 0, 0); \
      acc[1][0] = __builtin_amdgcn_mfma_i32_32x32x32_i8(a1, b0, acc[1][0], 0, 0, 0); \
      acc[1][1] = __builtin_amdgcn_mfma_i32_32x32x32_i8(a1, b1, acc[1][1], 0, 0, 0); \
    }                                                                          \
    __builtin_amdgcn_s_setprio(0);                                             \
    __builtin_amdgcn_sched_barrier(0);                                         \
    __builtin_amdgcn_s_barrier();   /* all waves done reading buf[cur] */      \
    __builtin_amdgcn_sched_barrier(0);                                         \
    if (t + 2 < (NT)) {                                                        \
      STAGE(cur, t + 2);                                                       \
      asm volatile("s_waitcnt vmcnt(8)" ::: "memory");  /* t+1 landed */       \
    } else {                                                                   \
      asm volatile("s_waitcnt vmcnt(0)" ::: "memory");  /* tail drain */       \
    }                                                                          \
    __builtin_amdgcn_sched_barrier(0);                                         \
    __builtin_amdgcn_s_barrier();   /* everyone's t+1 loads landed */          \
    __builtin_amdgcn_sched_barrier(0);                                         \
  }
#else
// reg-staged fallback (R17-verified): both matrices in LDS, K-major.
#define GEMM_PIPE(AROWS, BROWS, NT, Abase, Bbase)                              \
  int skq = tid >> 5;                                                          \
  int sr4 = (tid & 31) * 4;                                                    \
  int arow = wm * 64 + (lane & 31);                                            \
  int brow = wn * 64 + (lane & 31);                                            \
  int khalf = lane >> 5;                                                       \
  _Pragma("unroll 1") for (int t = 0; t < (NT); ++t) {                         \
    size_t kb = (size_t)t * 8 + skq;                                           \
    v4i ra[4], rb[4];                                                          \
    _Pragma("unroll") for (int i = 0; i < 4; ++i) {                            \
      ra[i] = *(const v4i*)((Abase) + (kb * (AROWS) + bm * 128 + sr4 + i) * 16); \
      rb[i] = *(const v4i*)((Bbase) + (kb * (BROWS) + bn * 128 + sr4 + i) * 16); \
    }                                                                          \
    __syncthreads();                                                           \
    _Pragma("unroll") for (int i = 0; i < 4; ++i) {                            \
      *(v4i*)(As + skq * 2048 + (sr4 + i) * 16) = ra[i];                       \
      *(v4i*)(Bs + skq * 2048 + (sr4 + i) * 16) = rb[i];                       \
    }                                                                          \
    __syncthreads();                                                           \
    _Pragma("unroll") for (int kk = 0; kk < 4; ++kk) {                         \
      const uint8_t* Ab = As + (kk * 2 + khalf) * 2048;                        \
      const uint8_t* Bb = Bs + (kk * 2 + khalf) * 2048;                        \
      v4i a0 = *(const v4i*)(Ab + arow * 16);                                  \
      v4i a1 = *(const v4i*)(Ab + (arow + 32) * 16);                           \
      v4i b0 = *(const v4i*)(Bb + brow * 16);                                  \
      v4i b1 = *(const v4i*)(Bb + (brow + 32) * 16);                           \
      acc[0][0] = __builtin_amdgcn_mfma_i32_32x32x32_i8(a0, b0, acc[0][0], 0, 0, 0); \
      acc[0][1] = __builtin_amdgcn_mfma_i32_32x32x32_i8(a0, b1, acc[0][1], 0, 0, 0); \
      acc[1][0] = __builtin_amdgcn_mfma_i32_32x32x32_i8(a1, b0, acc[1][0], 0, 0, 0); \
      acc[1][1] = __builtin_amdgcn_mfma_i32_32x32x32_i8(a1, b1, acc[1][1], 0, 0, 0); \
    }                                                                          \
    __syncthreads();                                                           \
  }
#endif

// ---------- MFMA encoder ----------
// h = xiT @ wi8T^T (exact i32); z = (h + b_enc + act0b >= 1).
__global__ __launch_bounds__(256) void k_enc_mfma(
    const uint8_t* __restrict__ A, const uint8_t* __restrict__ B,
    const float* __restrict__ b_enc, const float* __restrict__ act0b,
    float* __restrict__ z_out, uint8_t* __restrict__ zi8T) {
#ifdef HAVE_GLOAD_LDS
  __shared__ uint8_t As[2 * 16384];
  __shared__ uint8_t Bs[2 * 16384];
#else
  __shared__ uint8_t As[16384];
  __shared__ uint8_t Bs[16384];
#endif
  int tid = (int)threadIdx.x;
  int bn = (int)blockIdx.x;
  int bm = (int)blockIdx.y;
  int wv = __builtin_amdgcn_readfirstlane(tid >> 6);
  int lane = tid & 63;
  int wm = wv >> 1, wn = wv & 1;

  v16i acc[2][2];
#pragma unroll
  for (int i = 0; i < 2; ++i)
#pragma unroll
    for (int j = 0; j < 2; ++j) acc[i][j] = (v16i)0;

  GEMM_PIPE(Bn, Hpad, Dpad / 128, A, B)

  // epilogue (R13-verified layout): col=lane&31, row=(r&3)+8*(r>>2)+4*(lane>>5)
  int col0 = bn * 128 + wn * 64 + (lane & 31);
#pragma unroll
  for (int ni = 0; ni < 2; ++ni) {
    int j = col0 + ni * 32;
    int js = (j < Hn) ? j : (Hn - 1);
    float be = b_enc[js];
    float ab = act0b[js];
    bool jv = j < Hn;
#pragma unroll
    for (int mi = 0; mi < 2; ++mi) {
      int rbase = bm * 128 + wm * 64 + mi * 32;
#pragma unroll
      for (int r = 0; r < 16; ++r) {
        int rloc = (r & 3) + 8 * (r >> 2) + 4 * (lane >> 5);
        int b = rbase + rloc;
        // exact: integer-valued acc + b_enc, then + act0_bias (reference order)
        float h = ((float)acc[mi][ni][r] + be) + ab;
        bool zb = jv && (h >= 1.0f);
        if (jv) {
          z_out[(size_t)b * Hn + j] = zb ? 1.0f : 0.0f;
          zi8T[((size_t)(j >> 4) * Bn + b) * 16 + (j & 15)] = zb ? 1 : 0;
        }
      }
    }
  }
}

// ---------- MFMA decoder ----------
// xd = zi8T @ wtdT^T (exact i32); output = (xd + act3b >= 1).
__global__ __launch_bounds__(256) void k_dec_mfma(
    const uint8_t* __restrict__ A,   // zi8T planes [Hpad/16][Bn][16]
    const uint8_t* __restrict__ B,   // wtdT planes [Hpad/16][Dpad][16]
    const float* __restrict__ act3b, float* __restrict__ out) {
#ifdef HAVE_GLOAD_LDS
  __shared__ uint8_t As[2 * 16384];
  __shared__ uint8_t Bs[2 * 16384];
#else
  __shared__ uint8_t As[16384];
  __shared__ uint8_t Bs[16384];
#endif
  int tid = (int)threadIdx.x;
  int bn = (int)blockIdx.x;  // 0..39
  int bm = (int)blockIdx.y;  // 0..31
  int wv = __builtin_amdgcn_readfirstlane(tid >> 6);
  int lane = tid & 63;
  int wm = wv >> 1, wn = wv & 1;

  v16i acc[2][2];
#pragma unroll
  for (int i = 0; i < 2; ++i)
#pragma unroll
    for (int j = 0; j < 2; ++j) acc[i][j] = (v16i)0;

  GEMM_PIPE(Bn, Dpad, Hpad / 128, A, B)

  int col0 = bn * 128 + wn * 64 + (lane & 31);
#pragma unroll
  for (int ni = 0; ni < 2; ++ni) {
    int d = col0 + ni * 32;
    int ds = (d < Dn) ? d : (Dn - 1);
    float ab = act3b[ds];
    bool dv = d < Dn;
#pragma unroll
    for (int mi = 0; mi < 2; ++mi) {
      int rbase = bm * 128 + wm * 64 + mi * 32;
#pragma unroll
      for (int r = 0; r < 16; ++r) {
        int rloc = (r & 3) + 8 * (r >> 2) + 4 * (lane >> 5);
        int b = rbase + rloc;
        // exact: integer-valued acc + act3_bias (reference order)
        if (dv) out[(size_t)b * Dn + d] = (((float)acc[mi][ni][r] + ab) >= 1.0f) ? 1.0f : 0.0f;
      }
    }
  }
}

// ---------- fallback bit encoder ----------
__global__ __launch_bounds__(256) void k_enc_bit(const uint64_t* __restrict__ xb2,
                                                 const uint64_t* __restrict__ wbT,
                                                 const float* __restrict__ b_enc,
                                                 const float* __restrict__ act0b,
                                                 float* __restrict__ z_out,
                                                 uint8_t* __restrict__ zb8) {
  __shared__ uint64_t wl[XW][8];
  int tid = (int)threadIdx.x;
  int jg = (int)blockIdx.x;
  int j0 = jg << 3;
#pragma unroll
  for (int k = 0; k < 3; ++k) {
    int idx = k * 256 + tid;
    if (idx < XW * 8) {
      int w = idx >> 3, j = idx & 7;
      wl[w][j] = wbT[(size_t)w * Hpad + j0 + j];
    }
  }
  __syncthreads();
  int wv = __builtin_amdgcn_readfirstlane(tid >> 6);
  int lane = tid & 63;
  int bg = (int)blockIdx.y * 4 + wv;
  int b0 = (bg << 8) + lane;
  int acc[4][8] = {};
  const uint64_t* xp = xb2 + 2 * (size_t)b0;
#pragma unroll 1
  for (int w2 = 0; w2 < XW / 2; ++w2) {
    ulong2 xx[4];
#pragma unroll
    for (int i = 0; i < 4; ++i)
      xx[i] = *(const ulong2*)(xp + ((size_t)w2 * Bn + i * 64) * 2);
#pragma unroll
    for (int t2 = 0; t2 < 4; ++t2) {
      ulong2 wa = *(ulong2*)&wl[2 * w2][2 * t2];
      ulong2 wb = *(ulong2*)&wl[2 * w2 + 1][2 * t2];
#pragma unroll
      for (int i = 0; i < 4; ++i) {
        acc[i][2 * t2]     = popc_acc(xx[i].x & wa.x, acc[i][2 * t2]);
        acc[i][2 * t2 + 1] = popc_acc(xx[i].x & wa.y, acc[i][2 * t2 + 1]);
        acc[i][2 * t2]     = popc_acc(xx[i].y & wb.x, acc[i][2 * t2]);
        acc[i][2 * t2 + 1] = popc_acc(xx[i].y & wb.y, acc[i][2 * t2 + 1]);
      }
    }
  }
  float be[8], ab[8];
#pragma unroll
  for (int t = 0; t < 8; ++t) {
    int j = j0 + t;
    int js = (j < Hn) ? j : (Hn - 1);
    be[t] = b_enc[js];
    ab[t] = act0b[js];
  }
#pragma unroll
  for (int i = 0; i < 4; ++i) {
    int b = b0 + i * 64;
    uint32_t zbyte = 0;
    float zf[8];
#pragma unroll
    for (int t = 0; t < 8; ++t) {
      int j = j0 + t;
      float h = ((float)acc[i][t] + be[t]) + ab[t];
      bool zb = (j < Hn) && (h >= 1.0f);
      zbyte |= zb ? (1u << t) : 0u;
      zf[t] = zb ? 1.0f : 0.0f;
    }
    zb8[((size_t)(jg >> 2) * Bn + b) * 4 + (jg & 3)] = (uint8_t)zbyte;
    if (j0 < Hn) {
      float* zp = z_out + (size_t)b * Hn + j0;
      *(float4*)zp = make_float4(zf[0], zf[1], zf[2], zf[3]);
      *(float4*)(zp + 4) = make_float4(zf[4], zf[5], zf[6], zf[7]);
    }
  }
}

// ---------- fallback bit decoder ----------
__global__ __launch_bounds__(256, 6) void k_dec_bit(const uint32_t* __restrict__ zb32,
                                                    const uint32_t* __restrict__ wt32,
                                                    const float* __restrict__ act3b,
                                                    float* __restrict__ out) {
  __shared__ uint32_t tl[64][8];
  int tid = (int)threadIdx.x;
  int dc = (int)blockIdx.x;
  int d0 = dc << 3;
  {
#pragma unroll
    for (int k = 0; k < 2; ++k) {
      int e = k * 256 + tid;
      int hw = e >> 3, dl = e & 7;
      tl[hw][dl] = wt32[(size_t)hw * Dpad + d0 + dl];
    }
  }
  __syncthreads();
  int wv = __builtin_amdgcn_readfirstlane(tid >> 6);
  int lane = tid & 63;
  int bg = (int)blockIdx.y * 4 + wv;
  int b0 = (bg << 8) + lane;
  int acc[4][8] = {};
  const uint32_t* zp = zb32 + b0;
  uint32_t z0, z1, z2, z3, n0, n1, n2, n3;
  uint4 wA, wB, wAn, wBn;
  z0 = zp[0]; z1 = zp[64]; z2 = zp[128]; z3 = zp[192];
  wA = *(const uint4*)&tl[0][0];
  wB = *(const uint4*)&tl[0][4];
#define DEC_MAC()                                          \
  do {                                                     \
    acc[0][0] = __builtin_popcount(z0 & wA.x) + acc[0][0]; \
    acc[0][1] = __builtin_popcount(z0 & wA.y) + acc[0][1]; \
    acc[0][2] = __builtin_popcount(z0 & wA.z) + acc[0][2]; \
    acc[0][3] = __builtin_popcount(z0 & wA.w) + acc[0][3]; \
    acc[0][4] = __builtin_popcount(z0 & wB.x) + acc[0][4]; \
    acc[0][5] = __builtin_popcount(z0 & wB.y) + acc[0][5]; \
    acc[0][6] = __builtin_popcount(z0 & wB.z) + acc[0][6]; \
    acc[0][7] = __builtin_popcount(z0 & wB.w) + acc[0][7]; \
    acc[1][0] = __builtin_popcount(z1 & wA.x) + acc[1][0]; \
    acc[1][1] = __builtin_popcount(z1 & wA.y) + acc[1][1]; \
    acc[1][2] = __builtin_popcount(z1 & wA.z) + acc[1][2]; \
    acc[1][3] = __builtin_popcount(z1 & wA.w) + acc[1][3]; \
    acc[1][4] = __builtin_popcount(z1 & wB.x) + acc[1][4]; \
    acc[1][5] = __builtin_popcount(z1 & wB.y) + acc[1][5]; \
    acc[1][6] = __builtin_popcount(z1 & wB.z) + acc[1][6]; \
    acc[1][7] = __builtin_popcount(z1 & wB.w) + acc[1][7]; \
    acc[2][0] = __builtin_popcount(z2 & wA.x) + acc[2][0]; \
    acc[2][1] = __builtin_popcount(z2 & wA.y) + acc[2][1]; \
    acc[2][2] = __builtin_popcount(z2 & wA.z) + acc[2][2]; \
    acc[2][3] = __builtin_popcount(z2 & wA.w) + acc[2][3]; \
    acc[2][4] = __builtin_popcount(z2 & wB.x) + acc[2][4]; \
    acc[2][5] = __builtin_popcount(z2 & wB.y) + acc[2][5]; \
    acc[2][6] = __builtin_popcount(z2 & wB.z) + acc[2][6]; \
    acc[2][7] = __builtin_popcount(z2 & wB.w) + acc[2][7]; \
    acc[3][0] = __builtin_popcount(z3 & wA.x) + acc[3][0]; \
    acc[3][1] = __builtin_popcount(z3 & wA.y) + acc[3][1]; \
    acc[3][2] = __builtin_popcount(z3 & wA.z) + acc[3][2]; \
    acc[3][3] = __builtin_popcount(z3 & wA.w) + acc[3][3]; \
    acc[3][4] = __builtin_popcount(z3 & wB.x) + acc[3][4]; \
    acc[3][5] = __builtin_popcount(z3 & wB.y) + acc[3][5]; \
    acc[3][6] = __builtin_popcount(z3 & wB.z) + acc[3][6]; \
    acc[3][7] = __builtin_popcount(z3 & wB.w) + acc[3][7]; \
  } while (0)
#pragma unroll 1
  for (int hw = 0; hw < 64; ++hw) {
    int hn = (hw < 63) ? hw + 1 : hw;
    const uint32_t* zq = zp + (size_t)hn * Bn;
    n0 = zq[0]; n1 = zq[64]; n2 = zq[128]; n3 = zq[192];
    wAn = *(const uint4*)&tl[hn][0];
    wBn = *(const uint4*)&tl[hn][4];
    DEC_MAC();
    z0 = n0; z1 = n1; z2 = n2; z3 = n3;
    wA = wAn; wB = wBn;
  }
#undef DEC_MAC
  float ab[8];
#pragma unroll
  for (int t = 0; t < 8; ++t) {
    int d = d0 + t;
    int ds = (d < Dn) ? d : (Dn - 1);
    ab[t] = act3b[ds];
  }
  if (d0 < Dn) {
#pragma unroll
    for (int i = 0; i < 4; ++i) {
      int b = b0 + i * 64;
      float of[8];
#pragma unroll
      for (int t = 0; t < 8; ++t)
        of[t] = (((float)acc[i][t] + ab[t]) >= 1.0f) ? 1.0f : 0.0f;
      float* op = out + (size_t)b * Dn + d0;
      *(float4*)op = make_float4(of[0], of[1], of[2], of[3]);
      *(float4*)(op + 4) = make_float4(of[4], of[5], of[6], of[7]);
    }
  }
}

// ---------- classifier GEMM ----------
__global__ __launch_bounds__(256) void k_cls_i8(const uint8_t* __restrict__ zi8T,
                                                const float* __restrict__ fwT,
                                                float* __restrict__ cls) {
  __shared__ float zT[64][132];
  __shared__ float fwL[64][64];
  int tid = (int)threadIdx.x;
  int bb0 = (int)blockIdx.x * 128;
  int jsp = (int)blockIdx.y;
  int tx = tid & 15, ty = tid >> 4;
  float acc[8][4] = {};
  for (int tile = 0; tile < 4; ++tile) {
    int jt0 = jsp * 256 + tile * 64;
    __syncthreads();
#pragma unroll
    for (int k = 0; k < 8; ++k) {
      int idx = k * 256 + tid;
      int r = idx >> 4, c4 = idx & 15;
      int j = jt0 + c4 * 4;
      uchar4 v = make_uchar4(0, 0, 0, 0);
      if (j < Hn)
        v = *(const uchar4*)(zi8T + ((size_t)(j >> 4) * Bn + (bb0 + r)) * 16 + (j & 15));
      zT[c4 * 4 + 0][r] = (float)v.x;
      zT[c4 * 4 + 1][r] = (float)v.y;
      zT[c4 * 4 + 2][r] = (float)v.z;
      zT[c4 * 4 + 3][r] = (float)v.w;
    }
#pragma unroll
    for (int k = 0; k < 4; ++k) {
      int idx = k * 256 + tid;
      int jj = idx >> 4, c4 = idx & 15;
      int j = jt0 + jj;
      float4 v = make_float4(0.f, 0.f, 0.f, 0.f);
      if (j < Hn) v = *(const float4*)(fwT + (size_t)j * 64 + c4 * 4);
      *(float4*)&fwL[jj][c4 * 4] = v;
    }
    __syncthreads();
#pragma unroll 4
    for (int jj = 0; jj < 64; ++jj) {
      float4 fv = *(float4*)&fwL[jj][tx * 4];
      float4 za = *(float4*)&zT[jj][ty * 8];
      float4 zb = *(float4*)&zT[jj][ty * 8 + 4];
      float zz[8] = {za.x, za.y, za.z, za.w, zb.x, zb.y, zb.z, zb.w};
      float ff[4] = {fv.x, fv.y, fv.z, fv.w};
#pragma unroll
      for (int i = 0; i < 8; ++i)
#pragma unroll
        for (int l = 0; l < 4; ++l) acc[i][l] += zz[i] * ff[l];
    }
  }
#pragma unroll
  for (int i = 0; i < 8; ++i) {
    int b = bb0 + ty * 8 + i;
#pragma unroll
    for (int l = 0; l < 4; ++l) {
      int L = tx * 4 + l;
      if (L < Ln) atomicAdd(&cls[(size_t)b * Ln + L], acc[i][l]);
    }
  }
}

__global__ __launch_bounds__(256) void k_cls_f32(const float* __restrict__ z,
                                                 const float* __restrict__ fwT,
                                                 float* __restrict__ cls) {
  __shared__ float zT[64][132];
  __shared__ float fwL[64][64];
  int tid = (int)threadIdx.x;
  int bb0 = (int)blockIdx.x * 128;
  int jsp = (int)blockIdx.y;
  int tx = tid & 15, ty = tid >> 4;
  float acc[8][4] = {};
  for (int tile = 0; tile < 4; ++tile) {
    int jt0 = jsp * 256 + tile * 64;
    __syncthreads();
#pragma unroll
    for (int k = 0; k < 8; ++k) {
      int idx = k * 256 + tid;
      int r = idx >> 4, c4 = idx & 15;
      int j = jt0 + c4 * 4;
      float4 v = make_float4(0.f, 0.f, 0.f, 0.f);
      if (j < Hn) v = *(const float4*)(z + (size_t)(bb0 + r) * Hn + j);
      zT[c4 * 4 + 0][r] = v.x;
      zT[c4 * 4 + 1][r] = v.y;
      zT[c4 * 4 + 2][r] = v.z;
      zT[c4 * 4 + 3][r] = v.w;
    }
#pragma unroll
    for (int k = 0; k < 4; ++k) {
      int idx = k * 256 + tid;
      int jj = idx >> 4, c4 = idx & 15;
      int j = jt0 + jj;
      float4 v = make_float4(0.f, 0.f, 0.f, 0.f);
      if (j < Hn) v = *(const float4*)(fwT + (size_t)j * 64 + c4 * 4);
      *(float4*)&fwL[jj][c4 * 4] = v;
    }
    __syncthreads();
#pragma unroll 4
    for (int jj = 0; jj < 64; ++jj) {
      float4 fv = *(float4*)&fwL[jj][tx * 4];
      float4 za = *(float4*)&zT[jj][ty * 8];
      float4 zb = *(float4*)&zT[jj][ty * 8 + 4];
      float zz[8] = {za.x, za.y, za.z, za.w, zb.x, zb.y, zb.z, zb.w};
      float ff[4] = {fv.x, fv.y, fv.z, fv.w};
#pragma unroll
      for (int i = 0; i < 8; ++i)
#pragma unroll
        for (int l = 0; l < 4; ++l) acc[i][l] += zz[i] * ff[l];
    }
  }
#pragma unroll
  for (int i = 0; i < 8; ++i) {
    int b = bb0 + ty * 8 + i;
#pragma unroll
    for (int l = 0; l < 4; ++l) {
      int L = tx * 4 + l;
      if (L < Ln) atomicAdd(&cls[(size_t)b * Ln + L], acc[i][l]);
    }
  }
}

extern "C" void kernel_launch(void* const* d_in, const int* in_sizes, int n_in,
                              void* d_out, int out_size, void* d_ws, size_t ws_size,
                              hipStream_t stream) {
  const float* x     = (const float*)d_in[0];
  const float* W     = (const float*)d_in[1];
  const float* b_enc = (const float*)d_in[2];
  const float* act0b = (const float*)d_in[3];
  const float* act3b = (const float*)d_in[4];
  const float* cw    = (const float*)d_in[5];

  float* out0 = (float*)d_out;
  float* cls  = out0 + (size_t)Bn * Dn;
  float* zout = cls + (size_t)Bn * Ln;

  char* p = (char*)d_ws;
  uint32_t* zb32 = (uint32_t*)p; p += (size_t)64 * Bn * 4;   // 1.05 MB
  float*    fwT  = (float*)p;    p += (size_t)Hn * 64 * 4;   // 0.51 MB
  size_t common = (size_t)(p - (char*)d_ws);

  size_t sz_xi8 = (size_t)Bn * Dpad;    // 21.0 MB
  size_t sz_wi8 = (size_t)Hpad * Dpad;  // 10.5 MB
  size_t sz_zi8 = (size_t)Bn * Hpad;    //  8.4 MB
  size_t sz_wtd = (size_t)Dpad * Hpad;  // 10.5 MB
  size_t sz_wbT = (size_t)XW * Hpad * 8;
  size_t sz_wt32 = (size_t)64 * Dpad * 4;
  size_t full_need = common + sz_xi8 + sz_wi8 + sz_zi8 + sz_wtd;  // ~52 MB

  k_pack_fwT<<<(Hn * 64 + 255) / 256, 256, 0, stream>>>(cw, fwT);
  k_zero<<<(Bn * Ln + 255) / 256, 256, 0, stream>>>(cls, Bn * Ln);

  if (ws_size >= full_need) {
    uint8_t* xiT  = (uint8_t*)p;
    uint8_t* wi8T = xiT + sz_xi8;
    uint8_t* zi8T = wi8T + sz_wi8;
    uint8_t* wtdT = zi8T + sz_zi8;
    k_pack_xT<<<(Dpad / 16) * Bn / 256, 256, 0, stream>>>(x, xiT);
    dim3 gwd(Dpad / 256, Hpad / 64);  // (20, 32)
    k_pack_w_dualT<<<gwd, 256, 0, stream>>>(W, wi8T, wtdT);
    dim3 ge(Hpad / 128, Bn / 128);    // (16, 32)
    k_enc_mfma<<<ge, 256, 0, stream>>>(xiT, wi8T, b_enc, act0b, zout, zi8T);
    dim3 g3(32, 8);
    k_cls_i8<<<g3, 256, 0, stream>>>(zi8T, fwT, cls);
    dim3 gd(Dpad / 128, Bn / 128);    // (40, 32)
    k_dec_mfma<<<gd, 256, 0, stream>>>(zi8T, wtdT, act3b, out0);
  } else {
    uint64_t* wbT  = (uint64_t*)p;
    uint32_t* wt32 = (uint32_t*)(p + sz_wbT);
    uint64_t* xb2  = (uint64_t*)(p + sz_wbT + sz_wt32);
    {
      long long waves = (long long)Hn * (XW / 4);
      k_pack_w<<<(int)((waves * 64 + 255) / 256), 256, 0, stream>>>(W, wbT);
    }
    {
      long long waves = (long long)(Hpad / 64) * XW;
      k_transp<<<(int)((waves * 64 + 255) / 256), 256, 0, stream>>>(wbT, wt32);
    }
    {
      long long waves = (long long)Bn * (XW / 4);
      k_pack_x<<<(int)((waves * 64 + 255) / 256), 256, 0, stream>>>(x, xb2);
    }
    dim3 g1(256, 4);
    k_enc_bit<<<g1, 256, 0, stream>>>(xb2, wbT, b_enc, act0b, zout, (uint8_t*)zb32);
    dim3 g3(32, 8);
    k_cls_f32<<<g3, 256, 0, stream>>>(zout, fwT, cls);
    dim3 g2(640, 4);
    k_dec_bit<<<g2, 256, 0, stream>>>(zb32, wt32, act3b, out0);
  }
}

// Round 20
// 231.317 us; speedup vs baseline: 1.0485x; 1.0485x over previous
//
#include <hip/hip_runtime.h>
#include <stdint.h>

// Problem sizes.
static constexpr int Bn = 4096;
static constexpr int Dn = 5000;
static constexpr int Hn = 2000;
static constexpr int Ln = 50;
static constexpr int XW = 80;      // u64 words covering D (5120 bits)
static constexpr int Hpad = 2048;  // padded H
static constexpr int Dpad = 5120;  // padded D

typedef int v4i __attribute__((ext_vector_type(4)));
typedef int v16i __attribute__((ext_vector_type(16)));

#if defined(__has_builtin)
#if __has_builtin(__builtin_amdgcn_global_load_lds)
#define HAVE_GLOAD_LDS 1
#endif
#endif

#ifdef HAVE_GLOAD_LDS
__device__ __forceinline__ void gload16(const uint8_t* g, uint8_t* l) {
  // async global->LDS, 16B/lane; LDS dest = wave-uniform base + lane*16.
  __builtin_amdgcn_global_load_lds(
      (const __attribute__((address_space(1))) uint32_t*)g,
      (__attribute__((address_space(3))) uint32_t*)l, 16, 0, 0);
}
#endif

__device__ __forceinline__ int popc_acc(uint64_t v, int acc) {
  acc = __builtin_popcount((uint32_t)v) + acc;
  acc = __builtin_popcount((uint32_t)(v >> 32)) + acc;
  return acc;
}

// ---------- packing ----------
__global__ void k_pack_i8(const float* __restrict__ src, uint8_t* __restrict__ dst,
                          int nrows_out, int nrows_valid, int ncols_src) {
  int g = (int)blockIdx.x * 256 + (int)threadIdx.x;
  int row = g / (Dpad / 4);
  int c4 = g - row * (Dpad / 4);
  if (row >= nrows_out) return;
  int col = c4 * 4;
  uchar4 o = make_uchar4(0, 0, 0, 0);
  if (row < nrows_valid && col + 3 < ncols_src) {
    const float4 v = *(const float4*)(src + (size_t)row * ncols_src + col);
    o.x = v.x >= 0.5f; o.y = v.y >= 0.5f; o.z = v.z >= 0.5f; o.w = v.w >= 0.5f;
  }
  *(uchar4*)(dst + (size_t)row * Dpad + col) = o;
}

// One coalesced W pass -> wi8[j][d] (enc B) AND wtd[d][j] (dec B, i8 transposed).
__global__ __launch_bounds__(256) void k_pack_w_dual(const float* __restrict__ W,
                                                     uint8_t* __restrict__ wi8,
                                                     uint8_t* __restrict__ wtd) {
  int d = (int)blockIdx.x * 256 + (int)threadIdx.x;  // 0..5119
  int j0 = (int)blockIdx.y * 64;
  bool dv = d < Dn;
  uint64_t colbits = 0;
  for (int r = 0; r < 64; ++r) {
    int j = j0 + r;
    float v = (j < Hn && dv) ? W[(size_t)j * Dn + d] : 0.0f;
    uint8_t bit = (v >= 0.5f) ? 1 : 0;
    wi8[(size_t)j * Dpad + d] = bit;
    colbits |= ((uint64_t)bit) << r;
  }
  uint8_t* dst = wtd + (size_t)d * Hpad + j0;
#pragma unroll
  for (int q = 0; q < 4; ++q) {
    uint32_t u[4];
#pragma unroll
    for (int s = 0; s < 4; ++s) {
      uint32_t nib = (uint32_t)((colbits >> (q * 16 + s * 4)) & 0xFull);
      u[s] = (nib & 1u) | (((nib >> 1) & 1u) << 8) | (((nib >> 2) & 1u) << 16) |
             (((nib >> 3) & 1u) << 24);
    }
    *(uint4*)(dst + q * 16) = make_uint4(u[0], u[1], u[2], u[3]);
  }
}

// ---------- bit packing (fallback tier) ----------
__global__ void k_pack_x(const float* __restrict__ x, uint64_t* __restrict__ xb2) {
  int g = (int)((blockIdx.x * blockDim.x + threadIdx.x) >> 6);
  int lane = (int)(threadIdx.x & 63);
  constexpr int nq = XW >> 2;
  int row = g / nq;
  int q = g - row * nq;
  if (row >= Bn) return;
  int w0 = q << 2;
  unsigned long long m[4];
#pragma unroll
  for (int e = 0; e < 4; ++e) {
    int col = ((w0 + e) << 6) + lane;
    float v = (col < Dn) ? x[(size_t)row * Dn + col] : 0.0f;
    m[e] = __ballot(v >= 0.5f);
  }
  if (lane < 4) {
    unsigned long long mv = m[0];
    mv = (lane == 1) ? m[1] : mv;
    mv = (lane == 2) ? m[2] : mv;
    mv = (lane == 3) ? m[3] : mv;
    int w = w0 + lane;
    xb2[((size_t)(w >> 1) * Bn + row) * 2 + (w & 1)] = mv;
  }
}

__global__ void k_pack_w(const float* __restrict__ W, uint64_t* __restrict__ wbT) {
  int g = (int)((blockIdx.x * blockDim.x + threadIdx.x) >> 6);
  int lane = (int)(threadIdx.x & 63);
  constexpr int nq = XW >> 2;
  int row = g / nq;
  int q = g - row * nq;
  if (row >= Hn) return;
  int w0 = q << 2;
  unsigned long long m[4];
#pragma unroll
  for (int e = 0; e < 4; ++e) {
    int col = ((w0 + e) << 6) + lane;
    float v = (col < Dn) ? W[(size_t)row * Dn + col] : 0.0f;
    m[e] = __ballot(v >= 0.5f);
  }
  if (lane < 4) {
    unsigned long long mv = m[0];
    mv = (lane == 1) ? m[1] : mv;
    mv = (lane == 2) ? m[2] : mv;
    mv = (lane == 3) ? m[3] : mv;
    wbT[(size_t)(w0 + lane) * Hpad + row] = mv;
  }
}

__global__ void k_transp(const uint64_t* __restrict__ wbT, uint32_t* __restrict__ wt32) {
  int g = (int)((blockIdx.x * blockDim.x + threadIdx.x) >> 6);
  int lane = (int)(threadIdx.x & 63);
  int w = g % XW;
  int jc = g / XW;
  if (jc >= Hpad / 64) return;
  uint64_t word = wbT[(size_t)w * Hpad + jc * 64 + lane];
  uint64_t mym = 0;
#pragma unroll
  for (int e = 0; e < 64; ++e) {
    unsigned long long m = __ballot((word >> e) & 1ull);
    mym = (lane == e) ? m : mym;
  }
  int d = w * 64 + lane;
  wt32[(size_t)(jc * 2) * Dpad + d] = (uint32_t)mym;
  wt32[(size_t)(jc * 2 + 1) * Dpad + d] = (uint32_t)(mym >> 32);
}

__global__ void k_pack_fwT(const float* __restrict__ cw, float* __restrict__ fwT) {
  int idx = blockIdx.x * blockDim.x + threadIdx.x;
  if (idx >= Hn * 64) return;
  int j = idx >> 6, l = idx & 63;
  float v = 0.0f;
  if (l < Ln) {
    float t = 2.0f * cw[(size_t)l * Hn + j];
    v = 1.0f / (1.0f + expf(-t));
  }
  fwT[idx] = v;
}

__global__ void k_zero(float* __restrict__ p, int n) {
  int i = blockIdx.x * blockDim.x + threadIdx.x;
  if (i < n) p[i] = 0.0f;
}

// ================= BK=128 double-buffered pipelined i8 MFMA GEMM =================
// (R16-verified: session-best configuration, 231.8 us total.)
// Block tile 128x128, BK=128, 4 waves (2x2 of 64x64), LDS 2x(2x16KB)=64KB
// (2 blocks/CU). Prefetch(t+1) issued BEFORE compute(t): 8 gload16 fly under
// 32 MFMA (~290 cy) per wave; one vmcnt-drain barrier per tile.
// Swizzle: LDS[row][sq] = G[row][sq^(row&7)]; read slot kq^(row&7).

#ifdef HAVE_GLOAD_LDS
#define GEMM_PIPE(LDK, NT, Abase, Bbase)                                        \
  int srow8 = lane >> 3; /* 0..7 */                                            \
  int scol = (((lane & 7) ^ srow8) << 4);                                      \
  const uint8_t* aSrc[4];                                                      \
  const uint8_t* bSrc[4];                                                      \
  uint8_t* asd[2][4];                                                          \
  uint8_t* bsd[2][4];                                                          \
  _Pragma("unroll") for (int i = 0; i < 4; ++i) {                              \
    int rbaseS = i * 32 + wv * 8;                                              \
    aSrc[i] = (Abase) + (size_t)(bm * 128 + rbaseS + srow8) * (LDK) + scol;    \
    bSrc[i] = (Bbase) + (size_t)(bn * 128 + rbaseS + srow8) * (LDK) + scol;    \
    asd[0][i] = As + rbaseS * 128;                                             \
    asd[1][i] = As + 16384 + rbaseS * 128;                                     \
    bsd[0][i] = Bs + rbaseS * 128;                                             \
    bsd[1][i] = Bs + 16384 + rbaseS * 128;                                     \
  }                                                                            \
  int arow = wm * 64 + (lane & 31);                                            \
  int brow = wn * 64 + (lane & 31);                                            \
  int khalf = lane >> 5;                                                       \
  int asw = arow & 7; /* (arow+32)&7 == arow&7 */                              \
  int bsw = brow & 7;                                                          \
  /* prologue: stage tile 0 */                                                 \
  _Pragma("unroll") for (int i = 0; i < 4; ++i) {                              \
    gload16(aSrc[i], asd[0][i]);                                               \
    gload16(bSrc[i], bsd[0][i]);                                               \
  }                                                                            \
  __syncthreads();                                                             \
  _Pragma("unroll 1") for (int t = 0; t < (NT); ++t) {                         \
    int cur = t & 1;                                                           \
    if (t + 1 < (NT)) {                                                        \
      size_t koff = (size_t)(t + 1) * 128;                                     \
      _Pragma("unroll") for (int i = 0; i < 4; ++i) {                          \
        gload16(aSrc[i] + koff, asd[cur ^ 1][i]);                              \
        gload16(bSrc[i] + koff, bsd[cur ^ 1][i]);                              \
      }                                                                        \
    }                                                                          \
    const uint8_t* Ab = As + cur * 16384;                                      \
    const uint8_t* Bb = Bs + cur * 16384;                                      \
    _Pragma("unroll") for (int kk = 0; kk < 4; ++kk) {                         \
      int kq = kk * 2 + khalf;                                                 \
      v4i a0 = *(const v4i*)(Ab + arow * 128 + ((kq ^ asw) << 4));             \
      v4i a1 = *(const v4i*)(Ab + (arow + 32) * 128 + ((kq ^ asw) << 4));      \
      v4i b0 = *(const v4i*)(Bb + brow * 128 + ((kq ^ bsw) << 4));             \
      v4i b1 = *(const v4i*)(Bb + (brow + 32) * 128 + ((kq ^ bsw) << 4));      \
      acc[0][0] = __builtin_amdgcn_mfma_i32_32x32x32_i8(a0, b0, acc[0][0], 0, 0, 0); \
      acc[0][1] = __builtin_amdgcn_mfma_i32_32x32x32_i8(a0, b1, acc[0][1], 0, 0, 0); \
      acc[1][0] = __builtin_amdgcn_mfma_i32_32x32x32_i8(a1, b0, acc[1][0], 0, 0, 0); \
      acc[1][1] = __builtin_amdgcn_mfma_i32_32x32x32_i8(a1, b1, acc[1][1], 0, 0, 0); \
    }                                                                          \
    __syncthreads();                                                           \
  }
#else
// reg-staged fallback: single-buffer BK=64.
#define GEMM_PIPE(LDK, NT2, Abase, Bbase)                                      \
  int srow_l = tid >> 2; /* 0..63 */                                           \
  int sq = tid & 3;                                                            \
  const uint8_t* ap0 = (Abase) + (size_t)(bm * 128 + srow_l) * (LDK) + sq * 16;\
  const uint8_t* ap1 = ap0 + (size_t)64 * (LDK);                               \
  const uint8_t* bp0 = (Bbase) + (size_t)(bn * 128 + srow_l) * (LDK) + sq * 16;\
  const uint8_t* bp1 = bp0 + (size_t)64 * (LDK);                               \
  int lw0 = srow_l * 64 + ((sq ^ ((srow_l >> 1) & 3)) << 4);                   \
  int lw1 = (64 + srow_l) * 64 + ((sq ^ (((64 + srow_l) >> 1) & 3)) << 4);     \
  int arow = wm * 64 + (lane & 31);                                            \
  int brow = wn * 64 + (lane & 31);                                            \
  int khalf = lane >> 5;                                                       \
  int asl = (arow >> 1) & 3;                                                   \
  int bsl = (brow >> 1) & 3;                                                   \
  _Pragma("unroll 1") for (int t = 0; t < 2 * (NT2); ++t) {                    \
    size_t koff = (size_t)t * 64;                                              \
    v4i ra0 = *(const v4i*)(ap0 + koff);                                       \
    v4i ra1 = *(const v4i*)(ap1 + koff);                                       \
    v4i rb0 = *(const v4i*)(bp0 + koff);                                       \
    v4i rb1 = *(const v4i*)(bp1 + koff);                                       \
    __syncthreads();                                                           \
    *(v4i*)(As + lw0) = ra0;                                                   \
    *(v4i*)(As + lw1) = ra1;                                                   \
    *(v4i*)(Bs + lw0) = rb0;                                                   \
    *(v4i*)(Bs + lw1) = rb1;                                                   \
    __syncthreads();                                                           \
    _Pragma("unroll") for (int kk = 0; kk < 2; ++kk) {                         \
      int kq = kk * 2 + khalf;                                                 \
      v4i a0 = *(const v4i*)(As + arow * 64 + ((kq ^ asl) << 4));              \
      v4i a1 = *(const v4i*)(As + (arow + 32) * 64 + ((kq ^ asl) << 4));       \
      v4i b0 = *(const v4i*)(Bs + brow * 64 + ((kq ^ bsl) << 4));              \
      v4i b1 = *(const v4i*)(Bs + (brow + 32) * 64 + ((kq ^ bsl) << 4));       \
      acc[0][0] = __builtin_amdgcn_mfma_i32_32x32x32_i8(a0, b0, acc[0][0], 0, 0, 0); \
      acc[0][1] = __builtin_amdgcn_mfma_i32_32x32x32_i8(a0, b1, acc[0][1], 0, 0, 0); \
      acc[1][0] = __builtin_amdgcn_mfma_i32_32x32x32_i8(a1, b0, acc[1][0], 0, 0, 0); \
      acc[1][1] = __builtin_amdgcn_mfma_i32_32x32x32_i8(a1, b1, acc[1][1], 0, 0, 0); \
    }                                                                          \
  }
#endif

// ---------- MFMA encoder ----------
// h = xi8 @ wi8^T (exact i32); z = (h + b_enc + act0b >= 1).
__global__ __launch_bounds__(256) void k_enc_mfma(
    const uint8_t* __restrict__ A, const uint8_t* __restrict__ B,
    const float* __restrict__ b_enc, const float* __restrict__ act0b,
    float* __restrict__ z_out, uint8_t* __restrict__ zi8) {
#ifdef HAVE_GLOAD_LDS
  __shared__ uint8_t As[2 * 128 * 128];
  __shared__ uint8_t Bs[2 * 128 * 128];
#else
  __shared__ uint8_t As[128 * 64];
  __shared__ uint8_t Bs[128 * 64];
#endif
  int tid = (int)threadIdx.x;
  int bn = (int)blockIdx.x;
  int bm = (int)blockIdx.y;
  int wv = __builtin_amdgcn_readfirstlane(tid >> 6);
  int lane = tid & 63;
  int wm = wv >> 1, wn = wv & 1;

  v16i acc[2][2];
#pragma unroll
  for (int i = 0; i < 2; ++i)
#pragma unroll
    for (int j = 0; j < 2; ++j) acc[i][j] = (v16i)0;

  GEMM_PIPE(Dpad, Dpad / 128, A, B)

  // epilogue (R13-verified layout): col=lane&31, row=(r&3)+8*(r>>2)+4*(lane>>5)
  int col0 = bn * 128 + wn * 64 + (lane & 31);
#pragma unroll
  for (int ni = 0; ni < 2; ++ni) {
    int j = col0 + ni * 32;
    int js = (j < Hn) ? j : (Hn - 1);
    float be = b_enc[js];
    float ab = act0b[js];
    bool jv = j < Hn;
#pragma unroll
    for (int mi = 0; mi < 2; ++mi) {
      int rbase = bm * 128 + wm * 64 + mi * 32;
#pragma unroll
      for (int r = 0; r < 16; ++r) {
        int rloc = (r & 3) + 8 * (r >> 2) + 4 * (lane >> 5);
        int b = rbase + rloc;
        // exact: integer-valued acc + b_enc, then + act0_bias (reference order)
        float h = ((float)acc[mi][ni][r] + be) + ab;
        bool zb = jv && (h >= 1.0f);
        if (jv) {
          z_out[(size_t)b * Hn + j] = zb ? 1.0f : 0.0f;
          zi8[(size_t)b * Hpad + j] = zb ? 1 : 0;
        }
      }
    }
  }
}

// ---------- MFMA decoder ----------
// xd = zi8 @ wtd^T (exact i32); output = (xd + act3b >= 1).
__global__ __launch_bounds__(256) void k_dec_mfma(
    const uint8_t* __restrict__ A,   // zi8 [4096][2048]
    const uint8_t* __restrict__ B,   // wtd [5120][2048]
    const float* __restrict__ act3b, float* __restrict__ out) {
#ifdef HAVE_GLOAD_LDS
  __shared__ uint8_t As[2 * 128 * 128];
  __shared__ uint8_t Bs[2 * 128 * 128];
#else
  __shared__ uint8_t As[128 * 64];
  __shared__ uint8_t Bs[128 * 64];
#endif
  int tid = (int)threadIdx.x;
  int bn = (int)blockIdx.x;  // 0..39
  int bm = (int)blockIdx.y;  // 0..31
  int wv = __builtin_amdgcn_readfirstlane(tid >> 6);
  int lane = tid & 63;
  int wm = wv >> 1, wn = wv & 1;

  v16i acc[2][2];
#pragma unroll
  for (int i = 0; i < 2; ++i)
#pragma unroll
    for (int j = 0; j < 2; ++j) acc[i][j] = (v16i)0;

  GEMM_PIPE(Hpad, Hpad / 128, A, B)

  int col0 = bn * 128 + wn * 64 + (lane & 31);
#pragma unroll
  for (int ni = 0; ni < 2; ++ni) {
    int d = col0 + ni * 32;
    int ds = (d < Dn) ? d : (Dn - 1);
    float ab = act3b[ds];
    bool dv = d < Dn;
#pragma unroll
    for (int mi = 0; mi < 2; ++mi) {
      int rbase = bm * 128 + wm * 64 + mi * 32;
#pragma unroll
      for (int r = 0; r < 16; ++r) {
        int rloc = (r & 3) + 8 * (r >> 2) + 4 * (lane >> 5);
        int b = rbase + rloc;
        // exact: integer-valued acc + act3_bias (reference order)
        if (dv) out[(size_t)b * Dn + d] = (((float)acc[mi][ni][r] + ab) >= 1.0f) ? 1.0f : 0.0f;
      }
    }
  }
}

// ---------- fallback bit encoder ----------
__global__ __launch_bounds__(256) void k_enc_bit(const uint64_t* __restrict__ xb2,
                                                 const uint64_t* __restrict__ wbT,
                                                 const float* __restrict__ b_enc,
                                                 const float* __restrict__ act0b,
                                                 float* __restrict__ z_out,
                                                 uint8_t* __restrict__ zb8) {
  __shared__ uint64_t wl[XW][8];
  int tid = (int)threadIdx.x;
  int jg = (int)blockIdx.x;
  int j0 = jg << 3;
#pragma unroll
  for (int k = 0; k < 3; ++k) {
    int idx = k * 256 + tid;
    if (idx < XW * 8) {
      int w = idx >> 3, j = idx & 7;
      wl[w][j] = wbT[(size_t)w * Hpad + j0 + j];
    }
  }
  __syncthreads();
  int wv = __builtin_amdgcn_readfirstlane(tid >> 6);
  int lane = tid & 63;
  int bg = (int)blockIdx.y * 4 + wv;
  int b0 = (bg << 8) + lane;
  int acc[4][8] = {};
  const uint64_t* xp = xb2 + 2 * (size_t)b0;
#pragma unroll 1
  for (int w2 = 0; w2 < XW / 2; ++w2) {
    ulong2 xx[4];
#pragma unroll
    for (int i = 0; i < 4; ++i)
      xx[i] = *(const ulong2*)(xp + ((size_t)w2 * Bn + i * 64) * 2);
#pragma unroll
    for (int t2 = 0; t2 < 4; ++t2) {
      ulong2 wa = *(ulong2*)&wl[2 * w2][2 * t2];
      ulong2 wb = *(ulong2*)&wl[2 * w2 + 1][2 * t2];
#pragma unroll
      for (int i = 0; i < 4; ++i) {
        acc[i][2 * t2]     = popc_acc(xx[i].x & wa.x, acc[i][2 * t2]);
        acc[i][2 * t2 + 1] = popc_acc(xx[i].x & wa.y, acc[i][2 * t2 + 1]);
        acc[i][2 * t2]     = popc_acc(xx[i].y & wb.x, acc[i][2 * t2]);
        acc[i][2 * t2 + 1] = popc_acc(xx[i].y & wb.y, acc[i][2 * t2 + 1]);
      }
    }
  }
  float be[8], ab[8];
#pragma unroll
  for (int t = 0; t < 8; ++t) {
    int j = j0 + t;
    int js = (j < Hn) ? j : (Hn - 1);
    be[t] = b_enc[js];
    ab[t] = act0b[js];
  }
#pragma unroll
  for (int i = 0; i < 4; ++i) {
    int b = b0 + i * 64;
    uint32_t zbyte = 0;
    float zf[8];
#pragma unroll
    for (int t = 0; t < 8; ++t) {
      int j = j0 + t;
      float h = ((float)acc[i][t] + be[t]) + ab[t];
      bool zb = (j < Hn) && (h >= 1.0f);
      zbyte |= zb ? (1u << t) : 0u;
      zf[t] = zb ? 1.0f : 0.0f;
    }
    zb8[((size_t)(jg >> 2) * Bn + b) * 4 + (jg & 3)] = (uint8_t)zbyte;
    if (j0 < Hn) {
      float* zp = z_out + (size_t)b * Hn + j0;
      *(float4*)zp = make_float4(zf[0], zf[1], zf[2], zf[3]);
      *(float4*)(zp + 4) = make_float4(zf[4], zf[5], zf[6], zf[7]);
    }
  }
}

// ---------- fallback bit decoder ----------
__global__ __launch_bounds__(256, 6) void k_dec_bit(const uint32_t* __restrict__ zb32,
                                                    const uint32_t* __restrict__ wt32,
                                                    const float* __restrict__ act3b,
                                                    float* __restrict__ out) {
  __shared__ uint32_t tl[64][8];
  int tid = (int)threadIdx.x;
  int dc = (int)blockIdx.x;
  int d0 = dc << 3;
  {
#pragma unroll
    for (int k = 0; k < 2; ++k) {
      int e = k * 256 + tid;
      int hw = e >> 3, dl = e & 7;
      tl[hw][dl] = wt32[(size_t)hw * Dpad + d0 + dl];
    }
  }
  __syncthreads();
  int wv = __builtin_amdgcn_readfirstlane(tid >> 6);
  int lane = tid & 63;
  int bg = (int)blockIdx.y * 4 + wv;
  int b0 = (bg << 8) + lane;
  int acc[4][8] = {};
  const uint32_t* zp = zb32 + b0;
  uint32_t z0, z1, z2, z3, n0, n1, n2, n3;
  uint4 wA, wB, wAn, wBn;
  z0 = zp[0]; z1 = zp[64]; z2 = zp[128]; z3 = zp[192];
  wA = *(const uint4*)&tl[0][0];
  wB = *(const uint4*)&tl[0][4];
#define DEC_MAC()                                          \
  do {                                                     \
    acc[0][0] = __builtin_popcount(z0 & wA.x) + acc[0][0]; \
    acc[0][1] = __builtin_popcount(z0 & wA.y) + acc[0][1]; \
    acc[0][2] = __builtin_popcount(z0 & wA.z) + acc[0][2]; \
    acc[0][3] = __builtin_popcount(z0 & wA.w) + acc[0][3]; \
    acc[0][4] = __builtin_popcount(z0 & wB.x) + acc[0][4]; \
    acc[0][5] = __builtin_popcount(z0 & wB.y) + acc[0][5]; \
    acc[0][6] = __builtin_popcount(z0 & wB.z) + acc[0][6]; \
    acc[0][7] = __builtin_popcount(z0 & wB.w) + acc[0][7]; \
    acc[1][0] = __builtin_popcount(z1 & wA.x) + acc[1][0]; \
    acc[1][1] = __builtin_popcount(z1 & wA.y) + acc[1][1]; \
    acc[1][2] = __builtin_popcount(z1 & wA.z) + acc[1][2]; \
    acc[1][3] = __builtin_popcount(z1 & wA.w) + acc[1][3]; \
    acc[1][4] = __builtin_popcount(z1 & wB.x) + acc[1][4]; \
    acc[1][5] = __builtin_popcount(z1 & wB.y) + acc[1][5]; \
    acc[1][6] = __builtin_popcount(z1 & wB.z) + acc[1][6]; \
    acc[1][7] = __builtin_popcount(z1 & wB.w) + acc[1][7]; \
    acc[2][0] = __builtin_popcount(z2 & wA.x) + acc[2][0]; \
    acc[2][1] = __builtin_popcount(z2 & wA.y) + acc[2][1]; \
    acc[2][2] = __builtin_popcount(z2 & wA.z) + acc[2][2]; \
    acc[2][3] = __builtin_popcount(z2 & wA.w) + acc[2][3]; \
    acc[2][4] = __builtin_popcount(z2 & wB.x) + acc[2][4]; \
    acc[2][5] = __builtin_popcount(z2 & wB.y) + acc[2][5]; \
    acc[2][6] = __builtin_popcount(z2 & wB.z) + acc[2][6]; \
    acc[2][7] = __builtin_popcount(z2 & wB.w) + acc[2][7]; \
    acc[3][0] = __builtin_popcount(z3 & wA.x) + acc[3][0]; \
    acc[3][1] = __builtin_popcount(z3 & wA.y) + acc[3][1]; \
    acc[3][2] = __builtin_popcount(z3 & wA.z) + acc[3][2]; \
    acc[3][3] = __builtin_popcount(z3 & wA.w) + acc[3][3]; \
    acc[3][4] = __builtin_popcount(z3 & wB.x) + acc[3][4]; \
    acc[3][5] = __builtin_popcount(z3 & wB.y) + acc[3][5]; \
    acc[3][6] = __builtin_popcount(z3 & wB.z) + acc[3][6]; \
    acc[3][7] = __builtin_popcount(z3 & wB.w) + acc[3][7]; \
  } while (0)
#pragma unroll 1
  for (int hw = 0; hw < 64; ++hw) {
    int hn = (hw < 63) ? hw + 1 : hw;
    const uint32_t* zq = zp + (size_t)hn * Bn;
    n0 = zq[0]; n1 = zq[64]; n2 = zq[128]; n3 = zq[192];
    wAn = *(const uint4*)&tl[hn][0];
    wBn = *(const uint4*)&tl[hn][4];
    DEC_MAC();
    z0 = n0; z1 = n1; z2 = n2; z3 = n3;
    wA = wAn; wB = wBn;
  }
#undef DEC_MAC
  float ab[8];
#pragma unroll
  for (int t = 0; t < 8; ++t) {
    int d = d0 + t;
    int ds = (d < Dn) ? d : (Dn - 1);
    ab[t] = act3b[ds];
  }
  if (d0 < Dn) {
#pragma unroll
    for (int i = 0; i < 4; ++i) {
      int b = b0 + i * 64;
      float of[8];
#pragma unroll
      for (int t = 0; t < 8; ++t)
        of[t] = (((float)acc[i][t] + ab[t]) >= 1.0f) ? 1.0f : 0.0f;
      float* op = out + (size_t)b * Dn + d0;
      *(float4*)op = make_float4(of[0], of[1], of[2], of[3]);
      *(float4*)(op + 4) = make_float4(of[4], of[5], of[6], of[7]);
    }
  }
}

// ---------- classifier GEMM ----------
__global__ __launch_bounds__(256) void k_cls_i8(const uint8_t* __restrict__ zi8,
                                                const float* __restrict__ fwT,
                                                float* __restrict__ cls) {
  __shared__ float zT[64][132];
  __shared__ float fwL[64][64];
  int tid = (int)threadIdx.x;
  int bb0 = (int)blockIdx.x * 128;
  int jsp = (int)blockIdx.y;
  int tx = tid & 15, ty = tid >> 4;
  float acc[8][4] = {};
  for (int tile = 0; tile < 4; ++tile) {
    int jt0 = jsp * 256 + tile * 64;
    __syncthreads();
#pragma unroll
    for (int k = 0; k < 8; ++k) {
      int idx = k * 256 + tid;
      int r = idx >> 4, c4 = idx & 15;
      int j = jt0 + c4 * 4;
      uchar4 v = make_uchar4(0, 0, 0, 0);
      if (j < Hn) v = *(const uchar4*)(zi8 + (size_t)(bb0 + r) * Hpad + j);
      zT[c4 * 4 + 0][r] = (float)v.x;
      zT[c4 * 4 + 1][r] = (float)v.y;
      zT[c4 * 4 + 2][r] = (float)v.z;
      zT[c4 * 4 + 3][r] = (float)v.w;
    }
#pragma unroll
    for (int k = 0; k < 4; ++k) {
      int idx = k * 256 + tid;
      int jj = idx >> 4, c4 = idx & 15;
      int j = jt0 + jj;
      float4 v = make_float4(0.f, 0.f, 0.f, 0.f);
      if (j < Hn) v = *(const float4*)(fwT + (size_t)j * 64 + c4 * 4);
      *(float4*)&fwL[jj][c4 * 4] = v;
    }
    __syncthreads();
#pragma unroll 4
    for (int jj = 0; jj < 64; ++jj) {
      float4 fv = *(float4*)&fwL[jj][tx * 4];
      float4 za = *(float4*)&zT[jj][ty * 8];
      float4 zb = *(float4*)&zT[jj][ty * 8 + 4];
      float zz[8] = {za.x, za.y, za.z, za.w, zb.x, zb.y, zb.z, zb.w};
      float ff[4] = {fv.x, fv.y, fv.z, fv.w};
#pragma unroll
      for (int i = 0; i < 8; ++i)
#pragma unroll
        for (int l = 0; l < 4; ++l) acc[i][l] += zz[i] * ff[l];
    }
  }
#pragma unroll
  for (int i = 0; i < 8; ++i) {
    int b = bb0 + ty * 8 + i;
#pragma unroll
    for (int l = 0; l < 4; ++l) {
      int L = tx * 4 + l;
      if (L < Ln) atomicAdd(&cls[(size_t)b * Ln + L], acc[i][l]);
    }
  }
}

__global__ __launch_bounds__(256) void k_cls_f32(const float* __restrict__ z,
                                                 const float* __restrict__ fwT,
                                                 float* __restrict__ cls) {
  __shared__ float zT[64][132];
  __shared__ float fwL[64][64];
  int tid = (int)threadIdx.x;
  int bb0 = (int)blockIdx.x * 128;
  int jsp = (int)blockIdx.y;
  int tx = tid & 15, ty = tid >> 4;
  float acc[8][4] = {};
  for (int tile = 0; tile < 4; ++tile) {
    int jt0 = jsp * 256 + tile * 64;
    __syncthreads();
#pragma unroll
    for (int k = 0; k < 8; ++k) {
      int idx = k * 256 + tid;
      int r = idx >> 4, c4 = idx & 15;
      int j = jt0 + c4 * 4;
      float4 v = make_float4(0.f, 0.f, 0.f, 0.f);
      if (j < Hn) v = *(const float4*)(z + (size_t)(bb0 + r) * Hn + j);
      zT[c4 * 4 + 0][r] = v.x;
      zT[c4 * 4 + 1][r] = v.y;
      zT[c4 * 4 + 2][r] = v.z;
      zT[c4 * 4 + 3][r] = v.w;
    }
#pragma unroll
    for (int k = 0; k < 4; ++k) {
      int idx = k * 256 + tid;
      int jj = idx >> 4, c4 = idx & 15;
      int j = jt0 + jj;
      float4 v = make_float4(0.f, 0.f, 0.f, 0.f);
      if (j < Hn) v = *(const float4*)(fwT + (size_t)j * 64 + c4 * 4);
      *(float4*)&fwL[jj][c4 * 4] = v;
    }
    __syncthreads();
#pragma unroll 4
    for (int jj = 0; jj < 64; ++jj) {
      float4 fv = *(float4*)&fwL[jj][tx * 4];
      float4 za = *(float4*)&zT[jj][ty * 8];
      float4 zb = *(float4*)&zT[jj][ty * 8 + 4];
      float zz[8] = {za.x, za.y, za.z, za.w, zb.x, zb.y, zb.z, zb.w};
      float ff[4] = {fv.x, fv.y, fv.z, fv.w};
#pragma unroll
      for (int i = 0; i < 8; ++i)
#pragma unroll
        for (int l = 0; l < 4; ++l) acc[i][l] += zz[i] * ff[l];
    }
  }
#pragma unroll
  for (int i = 0; i < 8; ++i) {
    int b = bb0 + ty * 8 + i;
#pragma unroll
    for (int l = 0; l < 4; ++l) {
      int L = tx * 4 + l;
      if (L < Ln) atomicAdd(&cls[(size_t)b * Ln + L], acc[i][l]);
    }
  }
}

extern "C" void kernel_launch(void* const* d_in, const int* in_sizes, int n_in,
                              void* d_out, int out_size, void* d_ws, size_t ws_size,
                              hipStream_t stream) {
  const float* x     = (const float*)d_in[0];
  const float* W     = (const float*)d_in[1];
  const float* b_enc = (const float*)d_in[2];
  const float* act0b = (const float*)d_in[3];
  const float* act3b = (const float*)d_in[4];
  const float* cw    = (const float*)d_in[5];

  float* out0 = (float*)d_out;
  float* cls  = out0 + (size_t)Bn * Dn;
  float* zout = cls + (size_t)Bn * Ln;

  char* p = (char*)d_ws;
  uint32_t* zb32 = (uint32_t*)p; p += (size_t)64 * Bn * 4;   // 1.05 MB
  float*    fwT  = (float*)p;    p += (size_t)Hn * 64 * 4;   // 0.51 MB
  size_t common = (size_t)(p - (char*)d_ws);

  size_t sz_xi8 = (size_t)Bn * Dpad;    // 21.0 MB
  size_t sz_wi8 = (size_t)Hpad * Dpad;  // 10.5 MB
  size_t sz_zi8 = (size_t)Bn * Hpad;    //  8.4 MB
  size_t sz_wtd = (size_t)Dpad * Hpad;  // 10.5 MB
  size_t sz_wbT = (size_t)XW * Hpad * 8;
  size_t sz_wt32 = (size_t)64 * Dpad * 4;
  size_t full_need = common + sz_xi8 + sz_wi8 + sz_zi8 + sz_wtd;  // ~52 MB

  k_pack_fwT<<<(Hn * 64 + 255) / 256, 256, 0, stream>>>(cw, fwT);
  k_zero<<<(Bn * Ln + 255) / 256, 256, 0, stream>>>(cls, Bn * Ln);

  if (ws_size >= full_need) {
    uint8_t* xi8 = (uint8_t*)p;
    uint8_t* wi8 = xi8 + sz_xi8;
    uint8_t* zi8 = wi8 + sz_wi8;
    uint8_t* wtd = zi8 + sz_zi8;
    k_pack_i8<<<(Bn * (Dpad / 4) + 255) / 256, 256, 0, stream>>>(x, xi8, Bn, Bn, Dn);
    dim3 gwd(Dpad / 256, Hpad / 64);  // (20, 32)
    k_pack_w_dual<<<gwd, 256, 0, stream>>>(W, wi8, wtd);
    dim3 ge(Hpad / 128, Bn / 128);    // (16, 32)
    k_enc_mfma<<<ge, 256, 0, stream>>>(xi8, wi8, b_enc, act0b, zout, zi8);
    dim3 g3(32, 8);
    k_cls_i8<<<g3, 256, 0, stream>>>(zi8, fwT, cls);
    dim3 gd(Dpad / 128, Bn / 128);    // (40, 32)
    k_dec_mfma<<<gd, 256, 0, stream>>>(zi8, wtd, act3b, out0);
  } else {
    uint64_t* wbT  = (uint64_t*)p;
    uint32_t* wt32 = (uint32_t*)(p + sz_wbT);
    uint64_t* xb2  = (uint64_t*)(p + sz_wbT + sz_wt32);
    {
      long long waves = (long long)Hn * (XW / 4);
      k_pack_w<<<(int)((waves * 64 + 255) / 256), 256, 0, stream>>>(W, wbT);
    }
    {
      long long waves = (long long)(Hpad / 64) * XW;
      k_transp<<<(int)((waves * 64 + 255) / 256), 256, 0, stream>>>(wbT, wt32);
    }
    {
      long long waves = (long long)Bn * (XW / 4);
      k_pack_x<<<(int)((waves * 64 + 255) / 256), 256, 0, stream>>>(x, xb2);
    }
    dim3 g1(256, 4);
    k_enc_bit<<<g1, 256, 0, stream>>>(xb2, wbT, b_enc, act0b, zout, (uint8_t*)zb32);
    dim3 g3(32, 8);
    k_cls_f32<<<g3, 256, 0, stream>>>(zout, fwT, cls);
    dim3 g2(640, 4);
    k_dec_bit<<<g2, 256, 0, stream>>>(zb32, wt32, act3b, out0);
  }
}